// Round 13
// baseline (546.226 us; speedup 1.0000x reference)
//
#include <hip/hip_runtime.h>
#include <hip/hip_bf16.h>
#include <cstddef>

// ---------------------------------------------------------------------------
// 2-layer GCN: out = A_norm(relu(A_norm(x@W1)+b1) @ W2) + b2
// R8: GEMM2 fused into agg1 (k_agg1mm); scans merged; 7 dispatches.
// R9: fp32->bf16 via v_cvt_pk_bf16_f32 (inline asm; no builtin on gfx950).
// R10 (REGRESSED): flatmm GEMM1 -> latency chain. B needs LDS staging.
// R11 (VERIFIED 529us): B LDS-staged, A direct fp32; k_fused 154us.
// R14 (NEUTRAL, kept): dbuf Bs + counted vmcnt == R11 -> k_fused A-DELIVERY bound.
// R15: x->bf16 convert pass; k_fused 155 -> ~80us (A-delivery confirmed) but
//     histprep became top at 155us.
// R16 (NULL): convert coalescing remap 155 -> 155us. Traffic was identical
//     either way (L2 assembles lines); coalescing was never the cost.
// R18: theory = hist ATOMICS are histprep's long pole: WRITE_SIZE excess
//     (~47MB = 1.6M x 32B) shows device-scope atomicAdd RMWs at memory side,
//     and hist blocks were LAST in grid -> atomic drain serialized after
//     convert. Fix: hist blocks FIRST (atomic storm issues early, drains
//     under convert BW phase) + 4-edge chains (4 atomics in flight/thread,
//     1563 hist blocks). Also reveals agg1mm/agg2 in top-5 (never measured;
//     budget says agg1mm+agg2 ~ 280us = next target).
// R20: identical resubmission of R18 (rounds 11+12 both hit
//     GPUAcquisitionTimeout; still unmeasured). No stacked changes.
// ---------------------------------------------------------------------------

#define IN_F 512
#define HID 128
#define NCLS 32

typedef __attribute__((ext_vector_type(8))) short bf16x8;
typedef __attribute__((ext_vector_type(4))) float f32x4;

__device__ __forceinline__ unsigned short f2bf(float f) {
    union { float f; unsigned u; } v; v.f = f;
    unsigned r = v.u + 0x7fff + ((v.u >> 16) & 1);   // RNE
    return (unsigned short)(r >> 16);
}
__device__ __forceinline__ float bf2f(unsigned short h) {
    union { unsigned u; float f; } v; v.u = ((unsigned)h) << 16;
    return v.f;
}
__device__ __forceinline__ float lo16(unsigned u) { return bf2f((unsigned short)(u & 0xffff)); }
__device__ __forceinline__ float hi16(unsigned u) { return bf2f((unsigned short)(u >> 16)); }
// packed RNE convert: lo16(ret)=cvt(a), hi16(ret)=cvt(b)  [gfx950, no builtin]
__device__ __forceinline__ unsigned cvt_pk_bf16(float a, float b) {
    unsigned r;
    asm("v_cvt_pk_bf16_f32 %0, %1, %2" : "=v"(r) : "v"(a), "v"(b));
    return r;
}

// ---------------- hist (FIRST: atomics drain under convert) + W prep + x->bf16 ----------------
#define HCHUNK 1024
__global__ void k_histprep(const int* __restrict__ dst, int* __restrict__ deg,
                           int* __restrict__ rank, int E,
                           const float* __restrict__ W1, unsigned short* __restrict__ W1T,
                           const float* __restrict__ W2, unsigned short* __restrict__ W2T,
                           const float* __restrict__ x, unsigned short* __restrict__ xb,
                           int HB, int PB) {
    int b = blockIdx.x;
    if (b < HB) {
        // hist: 4 edges/thread, 4 independent atomics in flight
        int base = b * HCHUNK + threadIdx.x;
        int d[4];
        bool val[4];
#pragma unroll
        for (int j = 0; j < 4; ++j) {
            int e = base + j * 256;
            val[j] = e < E;
            if (val[j]) d[j] = dst[e];
        }
#pragma unroll
        for (int j = 0; j < 4; ++j)
            if (val[j]) rank[base + j * 256] = atomicAdd(&deg[d[j]], 1);
    } else if (b < HB + PB) {   // prep: W1T (65536) + W2T (4096) elements
        int i = (b - HB) * 256 + threadIdx.x;
        if (i < HID * IN_F) {
            int n = i >> 9, k = i & 511;
            W1T[(size_t)n * IN_F + k] = f2bf(W1[(size_t)k * HID + n]);
        } else {
            int j = i - HID * IN_F;
            int c = j >> 7, k = j & 127;           // W2T[c][k] = W2[k][c]
            W2T[(size_t)c * HID + k] = f2bf(W2[(size_t)k * NCLS + c]);
        }
    } else {
        // x -> bf16: block owns 1024 consecutive float4s; lane-contiguous
        size_t base = (size_t)(b - HB - PB) * 1024;       // in float4 units
        const float4* s4 = (const float4*)x + base;
        uint2* d2 = (uint2*)xb + base;
        int tid = threadIdx.x;
#pragma unroll
        for (int j = 0; j < 4; ++j) {
            float4 f = s4[j * 256 + tid];
            uint2 u;
            u.x = cvt_pk_bf16(f.x, f.y);
            u.y = cvt_pk_bf16(f.z, f.w);
            d2[j * 256 + tid] = u;
        }
    }
}

// ---------------- 2-level exclusive scan over PADDED counts ((deg+7)&~7) ----------------
__global__ __launch_bounds__(256) void k_scan1(const int* __restrict__ deg, int* __restrict__ rs,
                                               int* __restrict__ bsum, int n) {
    __shared__ int sd[256];
    int base = blockIdx.x * 2048 + threadIdx.x * 8;
    int v[8];
    int t = 0;
#pragma unroll
    for (int i = 0; i < 8; ++i) {
        int x = (base + i < n) ? ((deg[base + i] + 7) & ~7) : 0;
        v[i] = t;
        t += x;
    }
    sd[threadIdx.x] = t;
    __syncthreads();
    for (int off = 1; off < 256; off <<= 1) {
        int x = 0;
        if ((int)threadIdx.x >= off) x = sd[threadIdx.x - off];
        __syncthreads();
        if ((int)threadIdx.x >= off) sd[threadIdx.x] += x;
        __syncthreads();
    }
    int texcl = sd[threadIdx.x] - t;
#pragma unroll
    for (int i = 0; i < 8; ++i)
        if (base + i < n) rs[base + i] = texcl + v[i];
    if (threadIdx.x == 255) bsum[blockIdx.x] = sd[255];
}

// finalize rs (per-block scan of bsum), fill pad slots of csr with dummy index n,
// compute dinv, zero dummy hs/h2s rows.
__global__ __launch_bounds__(256) void k_scan3(int* __restrict__ rs, const int* __restrict__ bsum,
                                               const int* __restrict__ deg, int* __restrict__ csr,
                                               float* __restrict__ dinv,
                                               unsigned* __restrict__ hsu, unsigned* __restrict__ h2su,
                                               int n, int nb) {
    __shared__ int sb[256];
    __shared__ int se[256];
    int t = threadIdx.x;
    int val = (t < nb) ? bsum[t] : 0;
    sb[t] = val;
    __syncthreads();
    for (int off = 1; off < 256; off <<= 1) {
        int x = 0;
        if (t >= off) x = sb[t - off];
        __syncthreads();
        sb[t] += x;
        __syncthreads();
    }
    se[t] = sb[t] - val;        // exclusive block prefix
    __syncthreads();
    int i = blockIdx.x * 256 + t;
    if (i < n) {
        int d = deg[i];
        dinv[i] = rsqrtf((float)d + 1.0f);
        int r = rs[i] + se[i >> 11];
        rs[i] = r;
        int pc = (d + 7) & ~7;
        for (int j = d; j < pc; ++j) csr[r + j] = n;
    }
    if (blockIdx.x == 0) {
        if (t < 64) hsu[(size_t)n * 64 + t] = 0u;   // hs row N = 0
        if (t < 16) h2su[(size_t)n * 16 + t] = 0u;  // h2s row N = 0
    }
}

// ---------------- FUSED: GEMM1 (bf16 A direct, dbuf B, counted vmcnt) + scatter ----------
#define LSTR 40
#define SCHUNK 1024
__global__ __launch_bounds__(256) void k_fused(const unsigned short* __restrict__ XB,
                                               const unsigned short* __restrict__ BT,
                                               const float* __restrict__ dinv,
                                               unsigned short* __restrict__ C, int M,
                                               const int* __restrict__ src, const int* __restrict__ dst,
                                               const int* __restrict__ rank, const int* __restrict__ rs,
                                               int* __restrict__ csr, int E) {
    const int bid = blockIdx.x;
    const int tid = threadIdx.x;
    if (bid & 1) {
        // ---- scatter: csr[rs[dst]+rank] = src, no atomics, 4 chains in flight ----
        int base = (bid >> 1) * SCHUNK + tid;
        int d[4], s[4], rk[4];
        bool val[4];
#pragma unroll
        for (int j = 0; j < 4; ++j) {
            int e = base + j * 256;
            val[j] = e < E;
            if (val[j]) { d[j] = dst[e]; s[j] = src[e]; rk[j] = rank[e]; }
        }
#pragma unroll
        for (int j = 0; j < 4; ++j)
            if (val[j]) csr[rs[d[j]] + rk[j]] = s[j];
        return;
    }
    // ---- GEMM phase: bf16 A direct (16B/lane/step = the fragment), dbuf B ----
    __shared__ unsigned short Bs0[128 * LSTR];
    __shared__ unsigned short Bs1[128 * LSTR];
    const int wave = tid >> 6;
    const int lane = tid & 63;
    const int l16 = lane & 15;
    const int q = lane >> 4;
    const int rowBase = (bid >> 1) * 64;

    const int arow = rowBase + wave * 16 + l16;
    const bool aval = arow < M;
    const unsigned short* aptr = XB + (size_t)arow * IN_F + q * 8;

    // B staging mapping (verified)
    const int bn0 = tid >> 2, bn1 = 64 + (tid >> 2), bkc = tid & 3;
    const unsigned short* bp0 = BT + (size_t)bn0 * IN_F + bkc * 8;
    const unsigned short* bp1 = BT + (size_t)bn1 * IN_F + bkc * 8;
    unsigned short* w0 = Bs0 + bn0 * LSTR + bkc * 8;
    unsigned short* w1 = Bs0 + bn1 * LSTR + bkc * 8;
    unsigned short* w2 = Bs1 + bn0 * LSTR + bkc * 8;
    unsigned short* w3 = Bs1 + bn1 * LSTR + bkc * 8;

    f32x4 acc[8];
#pragma unroll
    for (int nt = 0; nt < 8; ++nt) acc[nt] = (f32x4){0.f, 0.f, 0.f, 0.f};

    uint4 za = make_uint4(0u, 0u, 0u, 0u);
    uint4 a0 = za, a1 = za;        // A[t] even/odd parity (bf16x8 each)
    uint4 b0a, b0b, b1a, b1b;      // B[t] even/odd parity

    // prologue: B[0]->Bs0; B[1],A[0],A[1] issued (stay in flight)
    b0a = *(const uint4*)(bp0);
    b0b = *(const uint4*)(bp1);
    if (aval) a0 = *(const uint4*)(aptr);
    *(uint4*)w0 = b0a;
    *(uint4*)w1 = b0b;
    b1a = *(const uint4*)(bp0 + 32);
    b1b = *(const uint4*)(bp1 + 32);
    if (aval) a1 = *(const uint4*)(aptr + 32);
    asm volatile("s_waitcnt lgkmcnt(0)" ::: "memory");
    __builtin_amdgcn_s_barrier();

#pragma unroll 1
    for (int tt = 0; tt < 8; ++tt) {
        const int k = tt * 64;
        // ======== even K-step t=2tt: compute from Bs0, stage B[t+1]->Bs1 ========
        *(uint4*)w2 = b1a;
        *(uint4*)w3 = b1b;
        {
            union { uint4 u; bf16x8 v; } af; af.u = a0;
            bf16x8 a_frag = af.v;
            if (tt < 7) {   // issue loads for step t+2 (reuse even-parity regs)
                b0a = *(const uint4*)(bp0 + k + 64);
                b0b = *(const uint4*)(bp1 + k + 64);
                if (aval) a0 = *(const uint4*)(aptr + k + 64);
            }
            bf16x8 bf0 = *(const bf16x8*)(Bs0 + (0 * 16 + l16) * LSTR + q * 8);
            bf16x8 bf1 = *(const bf16x8*)(Bs0 + (1 * 16 + l16) * LSTR + q * 8);
            bf16x8 bf2 = *(const bf16x8*)(Bs0 + (2 * 16 + l16) * LSTR + q * 8);
            bf16x8 bf3 = *(const bf16x8*)(Bs0 + (3 * 16 + l16) * LSTR + q * 8);
            bf16x8 bf4 = *(const bf16x8*)(Bs0 + (4 * 16 + l16) * LSTR + q * 8);
            bf16x8 bf5 = *(const bf16x8*)(Bs0 + (5 * 16 + l16) * LSTR + q * 8);
            bf16x8 bf6 = *(const bf16x8*)(Bs0 + (6 * 16 + l16) * LSTR + q * 8);
            bf16x8 bf7 = *(const bf16x8*)(Bs0 + (7 * 16 + l16) * LSTR + q * 8);
            acc[0] = __builtin_amdgcn_mfma_f32_16x16x32_bf16(a_frag, bf0, acc[0], 0, 0, 0);
            acc[1] = __builtin_amdgcn_mfma_f32_16x16x32_bf16(a_frag, bf1, acc[1], 0, 0, 0);
            acc[2] = __builtin_amdgcn_mfma_f32_16x16x32_bf16(a_frag, bf2, acc[2], 0, 0, 0);
            acc[3] = __builtin_amdgcn_mfma_f32_16x16x32_bf16(a_frag, bf3, acc[3], 0, 0, 0);
            acc[4] = __builtin_amdgcn_mfma_f32_16x16x32_bf16(a_frag, bf4, acc[4], 0, 0, 0);
            acc[5] = __builtin_amdgcn_mfma_f32_16x16x32_bf16(a_frag, bf5, acc[5], 0, 0, 0);
            acc[6] = __builtin_amdgcn_mfma_f32_16x16x32_bf16(a_frag, bf6, acc[6], 0, 0, 0);
            acc[7] = __builtin_amdgcn_mfma_f32_16x16x32_bf16(a_frag, bf7, acc[7], 0, 0, 0);
        }
        asm volatile("s_waitcnt lgkmcnt(0)" ::: "memory");
        __builtin_amdgcn_s_barrier();
        // ======== odd K-step t=2tt+1: compute from Bs1, stage B[t+1]->Bs0 ========
        if (tt < 7) {
            *(uint4*)w0 = b0a;
            *(uint4*)w1 = b0b;
        }
        {
            union { uint4 u; bf16x8 v; } af; af.u = a1;
            bf16x8 a_frag = af.v;
            if (tt < 7) {   // issue loads for step t+2 (reuse odd-parity regs)
                b1a = *(const uint4*)(bp0 + k + 96);
                b1b = *(const uint4*)(bp1 + k + 96);
                if (aval) a1 = *(const uint4*)(aptr + k + 96);
            }
            bf16x8 bf0 = *(const bf16x8*)(Bs1 + (0 * 16 + l16) * LSTR + q * 8);
            bf16x8 bf1 = *(const bf16x8*)(Bs1 + (1 * 16 + l16) * LSTR + q * 8);
            bf16x8 bf2 = *(const bf16x8*)(Bs1 + (2 * 16 + l16) * LSTR + q * 8);
            bf16x8 bf3 = *(const bf16x8*)(Bs1 + (3 * 16 + l16) * LSTR + q * 8);
            bf16x8 bf4 = *(const bf16x8*)(Bs1 + (4 * 16 + l16) * LSTR + q * 8);
            bf16x8 bf5 = *(const bf16x8*)(Bs1 + (5 * 16 + l16) * LSTR + q * 8);
            bf16x8 bf6 = *(const bf16x8*)(Bs1 + (6 * 16 + l16) * LSTR + q * 8);
            bf16x8 bf7 = *(const bf16x8*)(Bs1 + (7 * 16 + l16) * LSTR + q * 8);
            acc[0] = __builtin_amdgcn_mfma_f32_16x16x32_bf16(a_frag, bf0, acc[0], 0, 0, 0);
            acc[1] = __builtin_amdgcn_mfma_f32_16x16x32_bf16(a_frag, bf1, acc[1], 0, 0, 0);
            acc[2] = __builtin_amdgcn_mfma_f32_16x16x32_bf16(a_frag, bf2, acc[2], 0, 0, 0);
            acc[3] = __builtin_amdgcn_mfma_f32_16x16x32_bf16(a_frag, bf3, acc[3], 0, 0, 0);
            acc[4] = __builtin_amdgcn_mfma_f32_16x16x32_bf16(a_frag, bf4, acc[4], 0, 0, 0);
            acc[5] = __builtin_amdgcn_mfma_f32_16x16x32_bf16(a_frag, bf5, acc[5], 0, 0, 0);
            acc[6] = __builtin_amdgcn_mfma_f32_16x16x32_bf16(a_frag, bf6, acc[6], 0, 0, 0);
            acc[7] = __builtin_amdgcn_mfma_f32_16x16x32_bf16(a_frag, bf7, acc[7], 0, 0, 0);
        }
        if (tt < 7) {
            asm volatile("s_waitcnt lgkmcnt(0)" ::: "memory");
            __builtin_amdgcn_s_barrier();
        }
    }

#pragma unroll
    for (int r = 0; r < 4; ++r) {
        int row = rowBase + wave * 16 + q * 4 + r;
        if (row < M) {
            float sc = dinv[row];
#pragma unroll
            for (int nt = 0; nt < 8; ++nt)
                C[(size_t)row * HID + nt * 16 + l16] = f2bf(acc[nt][r] * sc);
        }
    }
}

// ---------------- agg1 + GEMM2 fused: block = 16 nodes; gather -> LDS h1 tile ->
// waves 0/1 do (16x128)@(128x32) via 4 MFMAs each -> h2s (dinv-scaled) -----------
__global__ __launch_bounds__(256) void k_agg1mm(const unsigned short* __restrict__ hs,
                                                const int* __restrict__ csr,
                                                const int* __restrict__ rs, const int* __restrict__ cnt,
                                                const float* __restrict__ dinv, const float* __restrict__ b1,
                                                const unsigned short* __restrict__ W2T,
                                                unsigned short* __restrict__ h2s, int N) {
    __shared__ unsigned h1s[16 * 68];   // 16 rows x 136 bf16 (stride 136 -> bank-clean)
    const int tid = threadIdx.x;
    const int wave = tid >> 6;
    const int lane = tid & 63;
    const int base = blockIdx.x * 16;
    const unsigned* hrow = (const unsigned*)hs;
    float2 bb = ((const float2*)b1)[lane];
#pragma unroll
    for (int r = 0; r < 4; ++r) {
        int slot = wave * 4 + r;
        int v = base + slot;
        float ox = 0.f, oy = 0.f;
        if (v < N) {
            float dv = dinv[v];
            unsigned u = hrow[(size_t)v * 64 + lane];   // self (pre-scaled)
            float ax = lo16(u), ay = hi16(u);
            int start = rs[v];
            int pc = (cnt[v] + 7) & ~7;
            for (int i = 0; i < pc; i += 8) {
                int s[8];
                unsigned uu[8];
#pragma unroll
                for (int j = 0; j < 8; ++j) s[j] = csr[start + i + j];
#pragma unroll
                for (int j = 0; j < 8; ++j) uu[j] = hrow[(size_t)s[j] * 64 + lane];
#pragma unroll
                for (int j = 0; j < 8; ++j) { ax += lo16(uu[j]); ay += hi16(uu[j]); }
            }
            ox = fmaxf(dv * ax + bb.x, 0.f);
            oy = fmaxf(dv * ay + bb.y, 0.f);
        }
        h1s[slot * 68 + lane] = cvt_pk_bf16(ox, oy);
    }
    __syncthreads();
    if (wave < 2) {     // wave w handles output cols [w*16, w*16+16)
        const int l16 = lane & 15;
        const int q = lane >> 4;
        f32x4 acc = (f32x4){0.f, 0.f, 0.f, 0.f};
        const unsigned short* h1b = (const unsigned short*)h1s;
#pragma unroll
        for (int ks = 0; ks < 4; ++ks) {
            bf16x8 af = *(const bf16x8*)(h1b + l16 * 136 + ks * 32 + q * 8);
            bf16x8 bf_ = *(const bf16x8*)(W2T + (size_t)(wave * 16 + l16) * HID + ks * 32 + q * 8);
            acc = __builtin_amdgcn_mfma_f32_16x16x32_bf16(af, bf_, acc, 0, 0, 0);
        }
#pragma unroll
        for (int r = 0; r < 4; ++r) {
            int v = base + q * 4 + r;
            if (v < N)
                h2s[(size_t)v * NCLS + wave * 16 + l16] = f2bf(acc[r] * dinv[v]);
        }
    }
}

// ---------------- agg2: 16 lanes per node (row = 1 cache line), branchless padded x8 ----------------
__global__ __launch_bounds__(256) void k_agg2(const unsigned short* __restrict__ h2s,
                                              const int* __restrict__ csr,
                                              const int* __restrict__ rs, const int* __restrict__ cnt,
                                              const float* __restrict__ dinv, const float* __restrict__ b2,
                                              float* __restrict__ out, int N) {
    int g = threadIdx.x >> 4;       // node slot 0..15
    int l = threadIdx.x & 15;       // 2 feats per lane
    int v = blockIdx.x * 16 + g;
    if (v >= N) return;
    float dv = dinv[v];
    const unsigned* rows = (const unsigned*)h2s;   // 16 uints per row
    unsigned u = rows[(size_t)v * 16 + l];         // self (pre-scaled)
    float ax = lo16(u), ay = hi16(u);
    int start = rs[v];
    int pc = (cnt[v] + 7) & ~7;
    for (int i = 0; i < pc; i += 8) {
        int s[8];
        unsigned uu[8];
#pragma unroll
        for (int j = 0; j < 8; ++j) s[j] = csr[start + i + j];
#pragma unroll
        for (int j = 0; j < 8; ++j) uu[j] = rows[(size_t)s[j] * 16 + l];
#pragma unroll
        for (int j = 0; j < 8; ++j) { ax += lo16(uu[j]); ay += hi16(uu[j]); }
    }
    float2 bb = ((const float2*)b2)[l];
    float2 o;
    o.x = dv * ax + bb.x;
    o.y = dv * ay + bb.y;
    *((float2*)(out + (size_t)v * NCLS) + l) = o;
}

// ---------------------------------------------------------------------------
extern "C" void kernel_launch(void* const* d_in, const int* in_sizes, int n_in,
                              void* d_out, int out_size, void* d_ws, size_t ws_size,
                              hipStream_t stream) {
    const float* x = (const float*)d_in[0];
    const int* edge_index = (const int*)d_in[1];
    const float* W1 = (const float*)d_in[2];
    const float* b1 = (const float*)d_in[3];
    const float* W2 = (const float*)d_in[4];
    const float* b2 = (const float*)d_in[5];
    float* out = (float*)d_out;

    const int N = in_sizes[0] / IN_F;       // 100000
    const int E = in_sizes[1] / 2;          // 1600000
    const int* e_src = edge_index;
    const int* e_dst = edge_index + E;

    char* ws = (char*)d_ws;
    size_t off = 0;
    auto alloc = [&](size_t bytes) -> char* {
        char* p = ws + off;
        off += (bytes + 255) & ~(size_t)255;
        return p;
    };
    int* deg             = (int*)alloc((size_t)N * 4);
    float* dinv          = (float*)alloc((size_t)N * 4);
    int* rs              = (int*)alloc((size_t)N * 4);
    int* bsum            = (int*)alloc(1024 * 4);
    int* csr             = (int*)alloc(((size_t)E + 8 * (size_t)N) * 4);  // padded CSR
    unsigned short* W1T  = (unsigned short*)alloc((size_t)HID * IN_F * 2);
    unsigned short* W2T  = (unsigned short*)alloc((size_t)NCLS * HID * 2);
    unsigned short* hs   = (unsigned short*)alloc((size_t)(N + 1) * HID * 2);  // +1 dummy zero row
    unsigned short* h2s  = (unsigned short*)alloc((size_t)(N + 1) * NCLS * 2); // +1 dummy zero row
    int* rank            = (int*)alloc((size_t)E * 4);
    unsigned short* xb   = (unsigned short*)alloc((size_t)N * IN_F * 2);       // x in bf16 (102.4 MB)

    const int nbN = (N + 255) / 256;
    const int nbScan = (N + 2047) / 2048;
    const int HB = (E + HCHUNK - 1) / HCHUNK;             // 1563 hist blocks (4 edges/thread)
    const int PB = (HID * IN_F + NCLS * HID) / 256;       // 272 prep blocks (W1T + W2T)
    const int XBb = (N * IN_F) / (256 * 16);              // 12500 convert blocks (1024 float4 each)
    const int NBG = (N + 63) / 64;                        // gemm tiles; scatter chunks same

    hipMemsetAsync(deg, 0, (size_t)N * 4, stream);
    k_histprep<<<HB + PB + XBb, 256, 0, stream>>>(e_dst, deg, rank, E, W1, W1T, W2, W2T,
                                                  x, xb, HB, PB);
    k_scan1<<<nbScan, 256, 0, stream>>>(deg, rs, bsum, N);
    k_scan3<<<nbN, 256, 0, stream>>>(rs, bsum, deg, csr, dinv, (unsigned*)hs, (unsigned*)h2s, N, nbScan);

    k_fused<<<2 * NBG, 256, 0, stream>>>(xb, W1T, dinv, hs, N, e_src, e_dst, rank, rs, csr, E);

    k_agg1mm<<<(N + 15) / 16, 256, 0, stream>>>(hs, csr, rs, deg, dinv, b1, W2T, h2s, N);
    k_agg2<<<(N + 15) / 16, 256, 0, stream>>>(h2s, csr, rs, deg, dinv, b2, out, N);
}

// Round 14
// 529.372 us; speedup vs baseline: 1.0318x; 1.0318x over previous
//
#include <hip/hip_runtime.h>
#include <hip/hip_bf16.h>
#include <cstddef>

// ---------------------------------------------------------------------------
// 2-layer GCN: out = A_norm(relu(A_norm(x@W1)+b1) @ W2) + b2
// R8: GEMM2 fused into agg1 (k_agg1mm); scans merged; 7 dispatches.
// R9: fp32->bf16 via v_cvt_pk_bf16_f32 (inline asm; no builtin on gfx950).
// R10 (REGRESSED): flatmm GEMM1 -> latency chain. B needs LDS staging.
// R11 (VERIFIED 529us): B LDS-staged, A direct fp32; k_fused 154us.
// R14 (NEUTRAL): dbuf Bs + counted vmcnt == R11.
// R15-R18 (NET LOSS, REVERTED): x->bf16 pre-pass. x is read ONCE by GEMM1;
//     converting it adds 205 MB of traffic to save 103. Convert builds
//     measured 536-546 vs non-convert 529-534. histprep reorder (R18) NULL.
// R21: revert to R11's verified k_fused (fp32 A + in-loop pk8, single Bs);
//     ONE new experiment: agg1mm 4-node-INTERLEAVED gather. Old loop was a
//     serial 2-hop chain (csr load -> hs gather) x ~2.5 iters x 4 nodes
//     sequentially per wave; new loop runs the 4 nodes in lockstep -> 32
//     gathers in flight (4x MLP, ~3x shorter chain). Inactive slots clamp
//     to dummy zero row N (zeroed in scan3); per-node FP order unchanged.
//     Budget says agg1mm+agg2 ~ 300us hides under k_fused's 154.
// ---------------------------------------------------------------------------

#define IN_F 512
#define HID 128
#define NCLS 32

typedef __attribute__((ext_vector_type(8))) short bf16x8;
typedef __attribute__((ext_vector_type(4))) float f32x4;

__device__ __forceinline__ unsigned short f2bf(float f) {
    union { float f; unsigned u; } v; v.f = f;
    unsigned r = v.u + 0x7fff + ((v.u >> 16) & 1);   // RNE
    return (unsigned short)(r >> 16);
}
__device__ __forceinline__ float bf2f(unsigned short h) {
    union { unsigned u; float f; } v; v.u = ((unsigned)h) << 16;
    return v.f;
}
__device__ __forceinline__ float lo16(unsigned u) { return bf2f((unsigned short)(u & 0xffff)); }
__device__ __forceinline__ float hi16(unsigned u) { return bf2f((unsigned short)(u >> 16)); }
// packed RNE convert: lo16(ret)=cvt(a), hi16(ret)=cvt(b)  [gfx950, no builtin]
__device__ __forceinline__ unsigned cvt_pk_bf16(float a, float b) {
    unsigned r;
    asm("v_cvt_pk_bf16_f32 %0, %1, %2" : "=v"(r) : "v"(a), "v"(b));
    return r;
}
// 8 fp32 -> bf16x8 fragment (4 cvt_pk instructions)
__device__ __forceinline__ bf16x8 pk8(float4 lo, float4 hi) {
    union { uint4 u; bf16x8 v; } r;
    r.u.x = cvt_pk_bf16(lo.x, lo.y);
    r.u.y = cvt_pk_bf16(lo.z, lo.w);
    r.u.z = cvt_pk_bf16(hi.x, hi.y);
    r.u.w = cvt_pk_bf16(hi.z, hi.w);
    return r.v;
}

// ---------------- hist (first, 4 atomic chains/thread) + W1/W2 transpose/cast ----------------
#define HCHUNK 1024
__global__ void k_histprep(const int* __restrict__ dst, int* __restrict__ deg,
                           int* __restrict__ rank, int E,
                           const float* __restrict__ W1, unsigned short* __restrict__ W1T,
                           const float* __restrict__ W2, unsigned short* __restrict__ W2T,
                           int HB) {
    int b = blockIdx.x;
    if (b < HB) {
        int base = b * HCHUNK + threadIdx.x;
        int d[4];
        bool val[4];
#pragma unroll
        for (int j = 0; j < 4; ++j) {
            int e = base + j * 256;
            val[j] = e < E;
            if (val[j]) d[j] = dst[e];
        }
#pragma unroll
        for (int j = 0; j < 4; ++j)
            if (val[j]) rank[base + j * 256] = atomicAdd(&deg[d[j]], 1);
    } else {   // prep: W1T (65536) + W2T (4096) elements
        int i = (b - HB) * 256 + threadIdx.x;
        if (i < HID * IN_F) {
            int n = i >> 9, k = i & 511;
            W1T[(size_t)n * IN_F + k] = f2bf(W1[(size_t)k * HID + n]);
        } else {
            int j = i - HID * IN_F;
            int c = j >> 7, k = j & 127;           // W2T[c][k] = W2[k][c]
            W2T[(size_t)c * HID + k] = f2bf(W2[(size_t)k * NCLS + c]);
        }
    }
}

// ---------------- 2-level exclusive scan over PADDED counts ((deg+7)&~7) ----------------
__global__ __launch_bounds__(256) void k_scan1(const int* __restrict__ deg, int* __restrict__ rs,
                                               int* __restrict__ bsum, int n) {
    __shared__ int sd[256];
    int base = blockIdx.x * 2048 + threadIdx.x * 8;
    int v[8];
    int t = 0;
#pragma unroll
    for (int i = 0; i < 8; ++i) {
        int x = (base + i < n) ? ((deg[base + i] + 7) & ~7) : 0;
        v[i] = t;
        t += x;
    }
    sd[threadIdx.x] = t;
    __syncthreads();
    for (int off = 1; off < 256; off <<= 1) {
        int x = 0;
        if ((int)threadIdx.x >= off) x = sd[threadIdx.x - off];
        __syncthreads();
        if ((int)threadIdx.x >= off) sd[threadIdx.x] += x;
        __syncthreads();
    }
    int texcl = sd[threadIdx.x] - t;
#pragma unroll
    for (int i = 0; i < 8; ++i)
        if (base + i < n) rs[base + i] = texcl + v[i];
    if (threadIdx.x == 255) bsum[blockIdx.x] = sd[255];
}

// finalize rs (per-block scan of bsum), fill pad slots of csr with dummy index n,
// compute dinv, zero dummy hs/h2s rows.
__global__ __launch_bounds__(256) void k_scan3(int* __restrict__ rs, const int* __restrict__ bsum,
                                               const int* __restrict__ deg, int* __restrict__ csr,
                                               float* __restrict__ dinv,
                                               unsigned* __restrict__ hsu, unsigned* __restrict__ h2su,
                                               int n, int nb) {
    __shared__ int sb[256];
    __shared__ int se[256];
    int t = threadIdx.x;
    int val = (t < nb) ? bsum[t] : 0;
    sb[t] = val;
    __syncthreads();
    for (int off = 1; off < 256; off <<= 1) {
        int x = 0;
        if (t >= off) x = sb[t - off];
        __syncthreads();
        sb[t] += x;
        __syncthreads();
    }
    se[t] = sb[t] - val;        // exclusive block prefix
    __syncthreads();
    int i = blockIdx.x * 256 + t;
    if (i < n) {
        int d = deg[i];
        dinv[i] = rsqrtf((float)d + 1.0f);
        int r = rs[i] + se[i >> 11];
        rs[i] = r;
        int pc = (d + 7) & ~7;
        for (int j = d; j < pc; ++j) csr[r + j] = n;
    }
    if (blockIdx.x == 0) {
        if (t < 64) hsu[(size_t)n * 64 + t] = 0u;   // hs row N = 0
        if (t < 16) h2su[(size_t)n * 16 + t] = 0u;  // h2s row N = 0
    }
}

// ---------------- FUSED: GEMM1 (B LDS-staged, A direct fp32) + scatter (odd blocks) ----------
#define LSTR 40
#define SCHUNK 1024
__global__ __launch_bounds__(256) void k_fused(const float* __restrict__ A,
                                               const unsigned short* __restrict__ BT,
                                               const float* __restrict__ dinv,
                                               unsigned short* __restrict__ C, int M,
                                               const int* __restrict__ src, const int* __restrict__ dst,
                                               const int* __restrict__ rank, const int* __restrict__ rs,
                                               int* __restrict__ csr, int E) {
    const int bid = blockIdx.x;
    const int tid = threadIdx.x;
    if (bid & 1) {
        // ---- scatter: csr[rs[dst]+rank] = src, no atomics, 4 chains in flight ----
        int base = (bid >> 1) * SCHUNK + tid;
        int d[4], s[4], rk[4];
        bool val[4];
#pragma unroll
        for (int j = 0; j < 4; ++j) {
            int e = base + j * 256;
            val[j] = e < E;
            if (val[j]) { d[j] = dst[e]; s[j] = src[e]; rk[j] = rank[e]; }
        }
#pragma unroll
        for (int j = 0; j < 4; ++j)
            if (val[j]) csr[rs[d[j]] + rk[j]] = s[j];
        return;
    }
    // ---- GEMM phase: B staged in LDS (verified mapping), A direct from global ----
    __shared__ unsigned short Bs[128 * LSTR];
    const int wave = tid >> 6;
    const int lane = tid & 63;
    const int l16 = lane & 15;
    const int q = lane >> 4;
    const int rowBase = (bid >> 1) * 64;

    const int arow = rowBase + wave * 16 + l16;
    const bool aval = arow < M;
    const float* aptr = A + (size_t)arow * IN_F + q * 8;

    const int bn0 = tid >> 2, bn1 = 64 + (tid >> 2), bkc = tid & 3;

    f32x4 acc[8];
#pragma unroll
    for (int nt = 0; nt < 8; ++nt) acc[nt] = (f32x4){0.f, 0.f, 0.f, 0.f};

    float4 a0, a1;
    uint4 pb0, pb1;
    auto ld = [&](int k0, float4& x0, float4& x1, uint4& b0, uint4& b1) {
        if (aval) {
            x0 = *(const float4*)(aptr + k0);
            x1 = *(const float4*)(aptr + k0 + 4);
        } else {
            x0 = make_float4(0.f, 0.f, 0.f, 0.f);
            x1 = x0;
        }
        b0 = *(const uint4*)(BT + (size_t)bn0 * IN_F + k0 + bkc * 8);
        b1 = *(const uint4*)(BT + (size_t)bn1 * IN_F + k0 + bkc * 8);
    };

    ld(0, a0, a1, pb0, pb1);

    for (int t = 0; t < 16; ++t) {
        *(uint4*)(Bs + bn0 * LSTR + bkc * 8) = pb0;
        *(uint4*)(Bs + bn1 * LSTR + bkc * 8) = pb1;
        __syncthreads();

        float4 na0, na1;
        uint4 nb0, nb1;
        if (t < 15) ld((t + 1) * 32, na0, na1, nb0, nb1);

        bf16x8 a_frag = pk8(a0, a1);
        bf16x8 b_frag[8];
#pragma unroll
        for (int nt = 0; nt < 8; ++nt)
            b_frag[nt] = *(const bf16x8*)(Bs + (nt * 16 + l16) * LSTR + q * 8);
#pragma unroll
        for (int nt = 0; nt < 8; ++nt)
            acc[nt] = __builtin_amdgcn_mfma_f32_16x16x32_bf16(a_frag, b_frag[nt], acc[nt], 0, 0, 0);
        __syncthreads();
        a0 = na0; a1 = na1; pb0 = nb0; pb1 = nb1;
    }

#pragma unroll
    for (int r = 0; r < 4; ++r) {
        int row = rowBase + wave * 16 + q * 4 + r;
        if (row < M) {
            float sc = dinv[row];
#pragma unroll
            for (int nt = 0; nt < 8; ++nt)
                C[(size_t)row * HID + nt * 16 + l16] = f2bf(acc[nt][r] * sc);
        }
    }
}

// ---------------- agg1 + GEMM2 fused: block = 16 nodes; wave handles its 4 nodes
// IN LOCKSTEP (32 gathers in flight, 4x MLP) -> LDS h1 tile -> waves 0/1 MFMA ----
__global__ __launch_bounds__(256) void k_agg1mm(const unsigned short* __restrict__ hs,
                                                const int* __restrict__ csr,
                                                const int* __restrict__ rs, const int* __restrict__ cnt,
                                                const float* __restrict__ dinv, const float* __restrict__ b1,
                                                const unsigned short* __restrict__ W2T,
                                                unsigned short* __restrict__ h2s, int N) {
    __shared__ unsigned h1s[16 * 68];   // 16 rows x 136 bf16 (stride 136 -> bank-clean)
    const int tid = threadIdx.x;
    const int wave = tid >> 6;
    const int lane = tid & 63;
    const int base = blockIdx.x * 16;   // N % 16 == 0 -> all nodes valid
    const unsigned* hrow = (const unsigned*)hs;
    float2 bb = ((const float2*)b1)[lane];

    // per-node state for the wave's 4 nodes
    float dv[4], ax[4], ay[4];
    int st[4], pcv[4];
#pragma unroll
    for (int r = 0; r < 4; ++r) {
        int v = base + wave * 4 + r;
        dv[r] = dinv[v];
        st[r] = rs[v];
        pcv[r] = (cnt[v] + 7) & ~7;
        unsigned u = hrow[(size_t)v * 64 + lane];   // self (pre-scaled)
        ax[r] = lo16(u);
        ay[r] = hi16(u);
    }
    int maxpc = max(max(pcv[0], pcv[1]), max(pcv[2], pcv[3]));

    for (int i = 0; i < maxpc; i += 8) {
        int s0[8], s1[8], s2[8], s3[8];
        const bool a0 = i < pcv[0], a1 = i < pcv[1], a2 = i < pcv[2], a3 = i < pcv[3];
#pragma unroll
        for (int j = 0; j < 8; ++j) s0[j] = a0 ? csr[st[0] + i + j] : N;
#pragma unroll
        for (int j = 0; j < 8; ++j) s1[j] = a1 ? csr[st[1] + i + j] : N;
#pragma unroll
        for (int j = 0; j < 8; ++j) s2[j] = a2 ? csr[st[2] + i + j] : N;
#pragma unroll
        for (int j = 0; j < 8; ++j) s3[j] = a3 ? csr[st[3] + i + j] : N;
        unsigned u0[8], u1[8], u2[8], u3[8];
#pragma unroll
        for (int j = 0; j < 8; ++j) u0[j] = hrow[(size_t)s0[j] * 64 + lane];
#pragma unroll
        for (int j = 0; j < 8; ++j) u1[j] = hrow[(size_t)s1[j] * 64 + lane];
#pragma unroll
        for (int j = 0; j < 8; ++j) u2[j] = hrow[(size_t)s2[j] * 64 + lane];
#pragma unroll
        for (int j = 0; j < 8; ++j) u3[j] = hrow[(size_t)s3[j] * 64 + lane];
#pragma unroll
        for (int j = 0; j < 8; ++j) { ax[0] += lo16(u0[j]); ay[0] += hi16(u0[j]); }
#pragma unroll
        for (int j = 0; j < 8; ++j) { ax[1] += lo16(u1[j]); ay[1] += hi16(u1[j]); }
#pragma unroll
        for (int j = 0; j < 8; ++j) { ax[2] += lo16(u2[j]); ay[2] += hi16(u2[j]); }
#pragma unroll
        for (int j = 0; j < 8; ++j) { ax[3] += lo16(u3[j]); ay[3] += hi16(u3[j]); }
    }
#pragma unroll
    for (int r = 0; r < 4; ++r) {
        float ox = fmaxf(dv[r] * ax[r] + bb.x, 0.f);
        float oy = fmaxf(dv[r] * ay[r] + bb.y, 0.f);
        h1s[(wave * 4 + r) * 68 + lane] = cvt_pk_bf16(ox, oy);
    }
    __syncthreads();
    if (wave < 2) {     // wave w handles output cols [w*16, w*16+16)
        const int l16 = lane & 15;
        const int q = lane >> 4;
        f32x4 acc = (f32x4){0.f, 0.f, 0.f, 0.f};
        const unsigned short* h1b = (const unsigned short*)h1s;
#pragma unroll
        for (int ks = 0; ks < 4; ++ks) {
            bf16x8 af = *(const bf16x8*)(h1b + l16 * 136 + ks * 32 + q * 8);
            bf16x8 bf_ = *(const bf16x8*)(W2T + (size_t)(wave * 16 + l16) * HID + ks * 32 + q * 8);
            acc = __builtin_amdgcn_mfma_f32_16x16x32_bf16(af, bf_, acc, 0, 0, 0);
        }
#pragma unroll
        for (int r = 0; r < 4; ++r) {
            int v = base + q * 4 + r;
            h2s[(size_t)v * NCLS + wave * 16 + l16] = f2bf(acc[r] * dinv[v]);
        }
    }
}

// ---------------- agg2: 16 lanes per node (row = 1 cache line), branchless padded x8 ----------------
__global__ __launch_bounds__(256) void k_agg2(const unsigned short* __restrict__ h2s,
                                              const int* __restrict__ csr,
                                              const int* __restrict__ rs, const int* __restrict__ cnt,
                                              const float* __restrict__ dinv, const float* __restrict__ b2,
                                              float* __restrict__ out, int N) {
    int g = threadIdx.x >> 4;       // node slot 0..15
    int l = threadIdx.x & 15;       // 2 feats per lane
    int v = blockIdx.x * 16 + g;
    if (v >= N) return;
    float dv = dinv[v];
    const unsigned* rows = (const unsigned*)h2s;   // 16 uints per row
    unsigned u = rows[(size_t)v * 16 + l];         // self (pre-scaled)
    float ax = lo16(u), ay = hi16(u);
    int start = rs[v];
    int pc = (cnt[v] + 7) & ~7;
    for (int i = 0; i < pc; i += 8) {
        int s[8];
        unsigned uu[8];
#pragma unroll
        for (int j = 0; j < 8; ++j) s[j] = csr[start + i + j];
#pragma unroll
        for (int j = 0; j < 8; ++j) uu[j] = rows[(size_t)s[j] * 16 + l];
#pragma unroll
        for (int j = 0; j < 8; ++j) { ax += lo16(uu[j]); ay += hi16(uu[j]); }
    }
    float2 bb = ((const float2*)b2)[l];
    float2 o;
    o.x = dv * ax + bb.x;
    o.y = dv * ay + bb.y;
    *((float2*)(out + (size_t)v * NCLS) + l) = o;
}

// ---------------------------------------------------------------------------
extern "C" void kernel_launch(void* const* d_in, const int* in_sizes, int n_in,
                              void* d_out, int out_size, void* d_ws, size_t ws_size,
                              hipStream_t stream) {
    const float* x = (const float*)d_in[0];
    const int* edge_index = (const int*)d_in[1];
    const float* W1 = (const float*)d_in[2];
    const float* b1 = (const float*)d_in[3];
    const float* W2 = (const float*)d_in[4];
    const float* b2 = (const float*)d_in[5];
    float* out = (float*)d_out;

    const int N = in_sizes[0] / IN_F;       // 100000
    const int E = in_sizes[1] / 2;          // 1600000
    const int* e_src = edge_index;
    const int* e_dst = edge_index + E;

    char* ws = (char*)d_ws;
    size_t off = 0;
    auto alloc = [&](size_t bytes) -> char* {
        char* p = ws + off;
        off += (bytes + 255) & ~(size_t)255;
        return p;
    };
    int* deg             = (int*)alloc((size_t)N * 4);
    float* dinv          = (float*)alloc((size_t)N * 4);
    int* rs              = (int*)alloc((size_t)N * 4);
    int* bsum            = (int*)alloc(1024 * 4);
    int* csr             = (int*)alloc(((size_t)E + 8 * (size_t)N) * 4);  // padded CSR
    unsigned short* W1T  = (unsigned short*)alloc((size_t)HID * IN_F * 2);
    unsigned short* W2T  = (unsigned short*)alloc((size_t)NCLS * HID * 2);
    unsigned short* hs   = (unsigned short*)alloc((size_t)(N + 1) * HID * 2);  // +1 dummy zero row
    unsigned short* h2s  = (unsigned short*)alloc((size_t)(N + 1) * NCLS * 2); // +1 dummy zero row
    int* rank            = (int*)alloc((size_t)E * 4);

    const int nbN = (N + 255) / 256;
    const int nbScan = (N + 2047) / 2048;
    const int HB = (E + HCHUNK - 1) / HCHUNK;             // 1563 hist blocks (4 edges/thread)
    const int PB = (HID * IN_F + NCLS * HID) / 256;       // 272 prep blocks (W1T + W2T)
    const int NBG = (N + 63) / 64;                        // gemm tiles; scatter chunks same

    hipMemsetAsync(deg, 0, (size_t)N * 4, stream);
    k_histprep<<<HB + PB, 256, 0, stream>>>(e_dst, deg, rank, E, W1, W1T, W2, W2T, HB);
    k_scan1<<<nbScan, 256, 0, stream>>>(deg, rs, bsum, N);
    k_scan3<<<nbN, 256, 0, stream>>>(rs, bsum, deg, csr, dinv, (unsigned*)hs, (unsigned*)h2s, N, nbScan);

    k_fused<<<2 * NBG, 256, 0, stream>>>(x, W1T, dinv, hs, N, e_src, e_dst, rank, rs, csr, E);

    k_agg1mm<<<(N + 15) / 16, 256, 0, stream>>>(hs, csr, rs, deg, dinv, b1, W2T, h2s, N);
    k_agg2<<<(N + 15) / 16, 256, 0, stream>>>(h2s, csr, rs, deg, dinv, b2, out, N);
}

// Round 20
// 522.281 us; speedup vs baseline: 1.0458x; 1.0136x over previous
//
#include <hip/hip_runtime.h>
#include <hip/hip_bf16.h>
#include <cstddef>

// ---------------------------------------------------------------------------
// 2-layer GCN: out = A_norm(relu(A_norm(x@W1)+b1) @ W2) + b2
// R11 (VERIFIED 529us): B LDS-staged, A direct fp32; k_fused 154us.
// R14 (NEUTRAL): counted-vmcnt dbuf == R11 -> NOT schedule/occupancy bound.
// R15-R18 (NET LOSS, REVERTED): x->bf16 pre-pass (x read once; +103MB net).
// R21 (NEUTRAL, kept): agg1mm 4-node lockstep gather; total 529.4 == 529.0.
// R22: SPLIT k_fused -> k_gemm + k_scatter. Theory: the fused scatter's 1.6M
//     random 4B csr writes (partial-line RMW; k_fused WRITE 81MB vs 25.6MB
//     accountable) saturate L2/fabric concurrently with GEMM A-reads -> A
//     delivery capped ~1.3TB/s regardless of schedule (explains R11==R14).
//     Split is also the diagnostic: per-kernel timing for both halves.
//     Pred: interference-real -> k_gemm 90-120us, scatter 25-60, total ~490;
//     null -> k_gemm ~150 alone -> pivot to BM=128 tile next.
// R27: identical resubmission of R22 (rounds 15-19 all GPUAcquisitionTimeout;
//     still unmeasured). Neutral-at-worst, positive-if-theory-right.
// ---------------------------------------------------------------------------

#define IN_F 512
#define HID 128
#define NCLS 32

typedef __attribute__((ext_vector_type(8))) short bf16x8;
typedef __attribute__((ext_vector_type(4))) float f32x4;

__device__ __forceinline__ unsigned short f2bf(float f) {
    union { float f; unsigned u; } v; v.f = f;
    unsigned r = v.u + 0x7fff + ((v.u >> 16) & 1);   // RNE
    return (unsigned short)(r >> 16);
}
__device__ __forceinline__ float bf2f(unsigned short h) {
    union { unsigned u; float f; } v; v.u = ((unsigned)h) << 16;
    return v.f;
}
__device__ __forceinline__ float lo16(unsigned u) { return bf2f((unsigned short)(u & 0xffff)); }
__device__ __forceinline__ float hi16(unsigned u) { return bf2f((unsigned short)(u >> 16)); }
// packed RNE convert: lo16(ret)=cvt(a), hi16(ret)=cvt(b)  [gfx950, no builtin]
__device__ __forceinline__ unsigned cvt_pk_bf16(float a, float b) {
    unsigned r;
    asm("v_cvt_pk_bf16_f32 %0, %1, %2" : "=v"(r) : "v"(a), "v"(b));
    return r;
}
// 8 fp32 -> bf16x8 fragment (4 cvt_pk instructions)
__device__ __forceinline__ bf16x8 pk8(float4 lo, float4 hi) {
    union { uint4 u; bf16x8 v; } r;
    r.u.x = cvt_pk_bf16(lo.x, lo.y);
    r.u.y = cvt_pk_bf16(lo.z, lo.w);
    r.u.z = cvt_pk_bf16(hi.x, hi.y);
    r.u.w = cvt_pk_bf16(hi.z, hi.w);
    return r.v;
}

// ---------------- hist (first, 4 atomic chains/thread) + W1/W2 transpose/cast ----------------
#define HCHUNK 1024
__global__ void k_histprep(const int* __restrict__ dst, int* __restrict__ deg,
                           int* __restrict__ rank, int E,
                           const float* __restrict__ W1, unsigned short* __restrict__ W1T,
                           const float* __restrict__ W2, unsigned short* __restrict__ W2T,
                           int HB) {
    int b = blockIdx.x;
    if (b < HB) {
        int base = b * HCHUNK + threadIdx.x;
        int d[4];
        bool val[4];
#pragma unroll
        for (int j = 0; j < 4; ++j) {
            int e = base + j * 256;
            val[j] = e < E;
            if (val[j]) d[j] = dst[e];
        }
#pragma unroll
        for (int j = 0; j < 4; ++j)
            if (val[j]) rank[base + j * 256] = atomicAdd(&deg[d[j]], 1);
    } else {   // prep: W1T (65536) + W2T (4096) elements
        int i = (b - HB) * 256 + threadIdx.x;
        if (i < HID * IN_F) {
            int n = i >> 9, k = i & 511;
            W1T[(size_t)n * IN_F + k] = f2bf(W1[(size_t)k * HID + n]);
        } else {
            int j = i - HID * IN_F;
            int c = j >> 7, k = j & 127;           // W2T[c][k] = W2[k][c]
            W2T[(size_t)c * HID + k] = f2bf(W2[(size_t)k * NCLS + c]);
        }
    }
}

// ---------------- 2-level exclusive scan over PADDED counts ((deg+7)&~7) ----------------
__global__ __launch_bounds__(256) void k_scan1(const int* __restrict__ deg, int* __restrict__ rs,
                                               int* __restrict__ bsum, int n) {
    __shared__ int sd[256];
    int base = blockIdx.x * 2048 + threadIdx.x * 8;
    int v[8];
    int t = 0;
#pragma unroll
    for (int i = 0; i < 8; ++i) {
        int x = (base + i < n) ? ((deg[base + i] + 7) & ~7) : 0;
        v[i] = t;
        t += x;
    }
    sd[threadIdx.x] = t;
    __syncthreads();
    for (int off = 1; off < 256; off <<= 1) {
        int x = 0;
        if ((int)threadIdx.x >= off) x = sd[threadIdx.x - off];
        __syncthreads();
        if ((int)threadIdx.x >= off) sd[threadIdx.x] += x;
        __syncthreads();
    }
    int texcl = sd[threadIdx.x] - t;
#pragma unroll
    for (int i = 0; i < 8; ++i)
        if (base + i < n) rs[base + i] = texcl + v[i];
    if (threadIdx.x == 255) bsum[blockIdx.x] = sd[255];
}

// finalize rs (per-block scan of bsum), fill pad slots of csr with dummy index n,
// compute dinv, zero dummy hs/h2s rows.
__global__ __launch_bounds__(256) void k_scan3(int* __restrict__ rs, const int* __restrict__ bsum,
                                               const int* __restrict__ deg, int* __restrict__ csr,
                                               float* __restrict__ dinv,
                                               unsigned* __restrict__ hsu, unsigned* __restrict__ h2su,
                                               int n, int nb) {
    __shared__ int sb[256];
    __shared__ int se[256];
    int t = threadIdx.x;
    int val = (t < nb) ? bsum[t] : 0;
    sb[t] = val;
    __syncthreads();
    for (int off = 1; off < 256; off <<= 1) {
        int x = 0;
        if (t >= off) x = sb[t - off];
        __syncthreads();
        sb[t] += x;
        __syncthreads();
    }
    se[t] = sb[t] - val;        // exclusive block prefix
    __syncthreads();
    int i = blockIdx.x * 256 + t;
    if (i < n) {
        int d = deg[i];
        dinv[i] = rsqrtf((float)d + 1.0f);
        int r = rs[i] + se[i >> 11];
        rs[i] = r;
        int pc = (d + 7) & ~7;
        for (int j = d; j < pc; ++j) csr[r + j] = n;
    }
    if (blockIdx.x == 0) {
        if (t < 64) hsu[(size_t)n * 64 + t] = 0u;   // hs row N = 0
        if (t < 16) h2su[(size_t)n * 16 + t] = 0u;  // h2s row N = 0
    }
}

// ---------------- GEMM1 standalone: B LDS-staged, A direct fp32 ----------
#define LSTR 40
__global__ __launch_bounds__(256) void k_gemm(const float* __restrict__ A,
                                              const unsigned short* __restrict__ BT,
                                              const float* __restrict__ dinv,
                                              unsigned short* __restrict__ C, int M) {
    const int bid = blockIdx.x;
    const int tid = threadIdx.x;
    __shared__ unsigned short Bs[128 * LSTR];
    const int wave = tid >> 6;
    const int lane = tid & 63;
    const int l16 = lane & 15;
    const int q = lane >> 4;
    const int rowBase = bid * 64;

    const int arow = rowBase + wave * 16 + l16;
    const bool aval = arow < M;
    const float* aptr = A + (size_t)arow * IN_F + q * 8;

    const int bn0 = tid >> 2, bn1 = 64 + (tid >> 2), bkc = tid & 3;

    f32x4 acc[8];
#pragma unroll
    for (int nt = 0; nt < 8; ++nt) acc[nt] = (f32x4){0.f, 0.f, 0.f, 0.f};

    float4 a0, a1;
    uint4 pb0, pb1;
    auto ld = [&](int k0, float4& x0, float4& x1, uint4& b0, uint4& b1) {
        if (aval) {
            x0 = *(const float4*)(aptr + k0);
            x1 = *(const float4*)(aptr + k0 + 4);
        } else {
            x0 = make_float4(0.f, 0.f, 0.f, 0.f);
            x1 = x0;
        }
        b0 = *(const uint4*)(BT + (size_t)bn0 * IN_F + k0 + bkc * 8);
        b1 = *(const uint4*)(BT + (size_t)bn1 * IN_F + k0 + bkc * 8);
    };

    ld(0, a0, a1, pb0, pb1);

    for (int t = 0; t < 16; ++t) {
        *(uint4*)(Bs + bn0 * LSTR + bkc * 8) = pb0;
        *(uint4*)(Bs + bn1 * LSTR + bkc * 8) = pb1;
        __syncthreads();

        float4 na0, na1;
        uint4 nb0, nb1;
        if (t < 15) ld((t + 1) * 32, na0, na1, nb0, nb1);

        bf16x8 a_frag = pk8(a0, a1);
        bf16x8 b_frag[8];
#pragma unroll
        for (int nt = 0; nt < 8; ++nt)
            b_frag[nt] = *(const bf16x8*)(Bs + (nt * 16 + l16) * LSTR + q * 8);
#pragma unroll
        for (int nt = 0; nt < 8; ++nt)
            acc[nt] = __builtin_amdgcn_mfma_f32_16x16x32_bf16(a_frag, b_frag[nt], acc[nt], 0, 0, 0);
        __syncthreads();
        a0 = na0; a1 = na1; pb0 = nb0; pb1 = nb1;
    }

#pragma unroll
    for (int r = 0; r < 4; ++r) {
        int row = rowBase + wave * 16 + q * 4 + r;
        if (row < M) {
            float sc = dinv[row];
#pragma unroll
            for (int nt = 0; nt < 8; ++nt)
                C[(size_t)row * HID + nt * 16 + l16] = f2bf(acc[nt][r] * sc);
        }
    }
}

// ---------------- scatter standalone: csr[rs[dst]+rank] = src, 4 chains ----------
#define SCHUNK 1024
__global__ __launch_bounds__(256) void k_scatter(const int* __restrict__ src, const int* __restrict__ dst,
                                                 const int* __restrict__ rank, const int* __restrict__ rs,
                                                 int* __restrict__ csr, int E) {
    int base = blockIdx.x * SCHUNK + threadIdx.x;
    int d[4], s[4], rk[4];
    bool val[4];
#pragma unroll
    for (int j = 0; j < 4; ++j) {
        int e = base + j * 256;
        val[j] = e < E;
        if (val[j]) { d[j] = dst[e]; s[j] = src[e]; rk[j] = rank[e]; }
    }
#pragma unroll
    for (int j = 0; j < 4; ++j)
        if (val[j]) csr[rs[d[j]] + rk[j]] = s[j];
}

// ---------------- agg1 + GEMM2 fused: block = 16 nodes; wave handles its 4 nodes
// IN LOCKSTEP (32 gathers in flight) -> LDS h1 tile -> waves 0/1 MFMA ----
__global__ __launch_bounds__(256) void k_agg1mm(const unsigned short* __restrict__ hs,
                                                const int* __restrict__ csr,
                                                const int* __restrict__ rs, const int* __restrict__ cnt,
                                                const float* __restrict__ dinv, const float* __restrict__ b1,
                                                const unsigned short* __restrict__ W2T,
                                                unsigned short* __restrict__ h2s, int N) {
    __shared__ unsigned h1s[16 * 68];   // 16 rows x 136 bf16 (stride 136 -> bank-clean)
    const int tid = threadIdx.x;
    const int wave = tid >> 6;
    const int lane = tid & 63;
    const int base = blockIdx.x * 16;   // N % 16 == 0 -> all nodes valid
    const unsigned* hrow = (const unsigned*)hs;
    float2 bb = ((const float2*)b1)[lane];

    float dv[4], ax[4], ay[4];
    int st[4], pcv[4];
#pragma unroll
    for (int r = 0; r < 4; ++r) {
        int v = base + wave * 4 + r;
        dv[r] = dinv[v];
        st[r] = rs[v];
        pcv[r] = (cnt[v] + 7) & ~7;
        unsigned u = hrow[(size_t)v * 64 + lane];   // self (pre-scaled)
        ax[r] = lo16(u);
        ay[r] = hi16(u);
    }
    int maxpc = max(max(pcv[0], pcv[1]), max(pcv[2], pcv[3]));

    for (int i = 0; i < maxpc; i += 8) {
        int s0[8], s1[8], s2[8], s3[8];
        const bool a0 = i < pcv[0], a1 = i < pcv[1], a2 = i < pcv[2], a3 = i < pcv[3];
#pragma unroll
        for (int j = 0; j < 8; ++j) s0[j] = a0 ? csr[st[0] + i + j] : N;
#pragma unroll
        for (int j = 0; j < 8; ++j) s1[j] = a1 ? csr[st[1] + i + j] : N;
#pragma unroll
        for (int j = 0; j < 8; ++j) s2[j] = a2 ? csr[st[2] + i + j] : N;
#pragma unroll
        for (int j = 0; j < 8; ++j) s3[j] = a3 ? csr[st[3] + i + j] : N;
        unsigned u0[8], u1[8], u2[8], u3[8];
#pragma unroll
        for (int j = 0; j < 8; ++j) u0[j] = hrow[(size_t)s0[j] * 64 + lane];
#pragma unroll
        for (int j = 0; j < 8; ++j) u1[j] = hrow[(size_t)s1[j] * 64 + lane];
#pragma unroll
        for (int j = 0; j < 8; ++j) u2[j] = hrow[(size_t)s2[j] * 64 + lane];
#pragma unroll
        for (int j = 0; j < 8; ++j) u3[j] = hrow[(size_t)s3[j] * 64 + lane];
#pragma unroll
        for (int j = 0; j < 8; ++j) { ax[0] += lo16(u0[j]); ay[0] += hi16(u0[j]); }
#pragma unroll
        for (int j = 0; j < 8; ++j) { ax[1] += lo16(u1[j]); ay[1] += hi16(u1[j]); }
#pragma unroll
        for (int j = 0; j < 8; ++j) { ax[2] += lo16(u2[j]); ay[2] += hi16(u2[j]); }
#pragma unroll
        for (int j = 0; j < 8; ++j) { ax[3] += lo16(u3[j]); ay[3] += hi16(u3[j]); }
    }
#pragma unroll
    for (int r = 0; r < 4; ++r) {
        float ox = fmaxf(dv[r] * ax[r] + bb.x, 0.f);
        float oy = fmaxf(dv[r] * ay[r] + bb.y, 0.f);
        h1s[(wave * 4 + r) * 68 + lane] = cvt_pk_bf16(ox, oy);
    }
    __syncthreads();
    if (wave < 2) {     // wave w handles output cols [w*16, w*16+16)
        const int l16 = lane & 15;
        const int q = lane >> 4;
        f32x4 acc = (f32x4){0.f, 0.f, 0.f, 0.f};
        const unsigned short* h1b = (const unsigned short*)h1s;
#pragma unroll
        for (int ks = 0; ks < 4; ++ks) {
            bf16x8 af = *(const bf16x8*)(h1b + l16 * 136 + ks * 32 + q * 8);
            bf16x8 bf_ = *(const bf16x8*)(W2T + (size_t)(wave * 16 + l16) * HID + ks * 32 + q * 8);
            acc = __builtin_amdgcn_mfma_f32_16x16x32_bf16(af, bf_, acc, 0, 0, 0);
        }
#pragma unroll
        for (int r = 0; r < 4; ++r) {
            int v = base + q * 4 + r;
            h2s[(size_t)v * NCLS + wave * 16 + l16] = f2bf(acc[r] * dinv[v]);
        }
    }
}

// ---------------- agg2: 16 lanes per node (row = 1 cache line), branchless padded x8 ----------------
__global__ __launch_bounds__(256) void k_agg2(const unsigned short* __restrict__ h2s,
                                              const int* __restrict__ csr,
                                              const int* __restrict__ rs, const int* __restrict__ cnt,
                                              const float* __restrict__ dinv, const float* __restrict__ b2,
                                              float* __restrict__ out, int N) {
    int g = threadIdx.x >> 4;       // node slot 0..15
    int l = threadIdx.x & 15;       // 2 feats per lane
    int v = blockIdx.x * 16 + g;
    if (v >= N) return;
    float dv = dinv[v];
    const unsigned* rows = (const unsigned*)h2s;   // 16 uints per row
    unsigned u = rows[(size_t)v * 16 + l];         // self (pre-scaled)
    float ax = lo16(u), ay = hi16(u);
    int start = rs[v];
    int pc = (cnt[v] + 7) & ~7;
    for (int i = 0; i < pc; i += 8) {
        int s[8];
        unsigned uu[8];
#pragma unroll
        for (int j = 0; j < 8; ++j) s[j] = csr[start + i + j];
#pragma unroll
        for (int j = 0; j < 8; ++j) uu[j] = rows[(size_t)s[j] * 16 + l];
#pragma unroll
        for (int j = 0; j < 8; ++j) { ax += lo16(uu[j]); ay += hi16(uu[j]); }
    }
    float2 bb = ((const float2*)b2)[l];
    float2 o;
    o.x = dv * ax + bb.x;
    o.y = dv * ay + bb.y;
    *((float2*)(out + (size_t)v * NCLS) + l) = o;
}

// ---------------------------------------------------------------------------
extern "C" void kernel_launch(void* const* d_in, const int* in_sizes, int n_in,
                              void* d_out, int out_size, void* d_ws, size_t ws_size,
                              hipStream_t stream) {
    const float* x = (const float*)d_in[0];
    const int* edge_index = (const int*)d_in[1];
    const float* W1 = (const float*)d_in[2];
    const float* b1 = (const float*)d_in[3];
    const float* W2 = (const float*)d_in[4];
    const float* b2 = (const float*)d_in[5];
    float* out = (float*)d_out;

    const int N = in_sizes[0] / IN_F;       // 100000
    const int E = in_sizes[1] / 2;          // 1600000
    const int* e_src = edge_index;
    const int* e_dst = edge_index + E;

    char* ws = (char*)d_ws;
    size_t off = 0;
    auto alloc = [&](size_t bytes) -> char* {
        char* p = ws + off;
        off += (bytes + 255) & ~(size_t)255;
        return p;
    };
    int* deg             = (int*)alloc((size_t)N * 4);
    float* dinv          = (float*)alloc((size_t)N * 4);
    int* rs              = (int*)alloc((size_t)N * 4);
    int* bsum            = (int*)alloc(1024 * 4);
    int* csr             = (int*)alloc(((size_t)E + 8 * (size_t)N) * 4);  // padded CSR
    unsigned short* W1T  = (unsigned short*)alloc((size_t)HID * IN_F * 2);
    unsigned short* W2T  = (unsigned short*)alloc((size_t)NCLS * HID * 2);
    unsigned short* hs   = (unsigned short*)alloc((size_t)(N + 1) * HID * 2);  // +1 dummy zero row
    unsigned short* h2s  = (unsigned short*)alloc((size_t)(N + 1) * NCLS * 2); // +1 dummy zero row
    int* rank            = (int*)alloc((size_t)E * 4);

    const int nbN = (N + 255) / 256;
    const int nbScan = (N + 2047) / 2048;
    const int HB = (E + HCHUNK - 1) / HCHUNK;             // 1563 hist blocks (4 edges/thread)
    const int PB = (HID * IN_F + NCLS * HID) / 256;       // 272 prep blocks (W1T + W2T)
    const int NBG = (N + 63) / 64;                        // 1563 gemm tiles
    const int SB = (E + SCHUNK - 1) / SCHUNK;             // 1563 scatter blocks

    hipMemsetAsync(deg, 0, (size_t)N * 4, stream);
    k_histprep<<<HB + PB, 256, 0, stream>>>(e_dst, deg, rank, E, W1, W1T, W2, W2T, HB);
    k_scan1<<<nbScan, 256, 0, stream>>>(deg, rs, bsum, N);
    k_scan3<<<nbN, 256, 0, stream>>>(rs, bsum, deg, csr, dinv, (unsigned*)hs, (unsigned*)h2s, N, nbScan);

    k_gemm<<<NBG, 256, 0, stream>>>(x, W1T, dinv, hs, N);
    k_scatter<<<SB, 256, 0, stream>>>(e_src, e_dst, rank, rs, csr, E);

    k_agg1mm<<<(N + 15) / 16, 256, 0, stream>>>(hs, csr, rs, deg, dinv, b1, W2T, h2s, N);
    k_agg2<<<(N + 15) / 16, 256, 0, stream>>>(h2s, csr, rs, deg, dinv, b2, out, N);
}